// Round 5
// baseline (477.711 us; speedup 1.0000x reference)
//
#include <hip/hip_runtime.h>
#include <hip/hip_cooperative_groups.h>

namespace cg = cooperative_groups;

#define N_NODES 50000
#define N_EDGES 800000
#define KPTS 15
#define IN_DIM 32
#define OUT_DIM 64
#define KP_EXTENT 0.6f

#define GRID 256                         // 1 block/CU -> co-residency guaranteed
#define BLOCK 256
#define NTHREADS (GRID * BLOCK)          // 65536
#define NKEY (4 * N_NODES)               // key = (k&3)*N_NODES + d
#define SCAN_CHUNK 512
#define SCAN_BLOCKS ((NKEY + SCAN_CHUNK - 1) / SCAN_CHUNK)   // 391
#define NBATCH ((N_NODES + 31) / 32)     // 1563 batches of 32 dst nodes
#define ECAP (1 << 22)                   // 4M entry capacity (real ~194k)

// ws layout (bytes)
#define CNT_OFF 0                        // int[NKEY]
#define OFF_OFF 800000                   // int[NKEY+1]
#define CUR_OFF 1600004                  // int[NKEY]
#define BSUM_OFF 2400004                 // int[512]
#define BPRE_OFF 2402052                 // int[513]
#define ENT_OFF 2404104                  // uint2[ECAP]  (8B aligned)

__device__ __forceinline__ void edge_geom(
    const float* __restrict__ pos, int s, int d,
    float& yx, float& yy, float& yz)
{
    yx = pos[s * 3 + 0] - pos[d * 3 + 0];
    yy = pos[s * 3 + 1] - pos[d * 3 + 1];
    yz = pos[s * 3 + 2] - pos[d * 3 + 2];
}

__global__ __launch_bounds__(BLOCK) void kpconv_fused(
    const float* __restrict__ pos,
    const float* __restrict__ feat,
    const float* __restrict__ kp,
    const float* __restrict__ W,        // [15][32][64]
    const int*   __restrict__ esrc,
    const int*   __restrict__ edst,
    int*   __restrict__ cnt,
    int*   __restrict__ off,            // NKEY+1
    int*   __restrict__ cursor,
    int*   __restrict__ bsum,
    int*   __restrict__ bpre,
    uint2* __restrict__ entries,
    float* __restrict__ out)
{
    cg::grid_group grid = cg::this_grid();
    const int tid = threadIdx.x;
    const int g   = blockIdx.x * BLOCK + tid;

    __shared__ float sacc[4 * 32 * OUT_DIM];   // 32 KB
    __shared__ int   sc[BLOCK];

    // ---------------- P1: count active (k,dst) pairs per key -------------
    for (int e = g; e < N_EDGES; e += NTHREADS) {
        const int s = esrc[e];
        const int d = edst[e];
        float yx, yy, yz;
        edge_geom(pos, s, d, yx, yy, yz);
        #pragma unroll
        for (int k = 0; k < KPTS; ++k) {
            const float dx = yx - kp[k * 3 + 0];
            const float dy = yy - kp[k * 3 + 1];
            const float dz = yz - kp[k * 3 + 2];
            const float dist = sqrtf(dx * dx + dy * dy + dz * dz);
            if (1.0f - dist * (1.0f / KP_EXTENT) > 0.0f)
                atomicAdd(&cnt[(k & 3) * N_NODES + d], 1);
        }
    }
    grid.sync();

    // ---------------- P2a: per-chunk local exclusive scan (grid-stride) ---
    for (int b = blockIdx.x; b < SCAN_BLOCKS; b += GRID) {
        __syncthreads();                       // protect sc reuse across iters
        const int k0 = b * SCAN_CHUNK + 2 * tid;
        int c0 = (k0     < NKEY) ? cnt[k0]     : 0;
        int c1 = (k0 + 1 < NKEY) ? cnt[k0 + 1] : 0;
        sc[tid] = c0 + c1;
        __syncthreads();
        for (int o = 1; o < BLOCK; o <<= 1) {
            const int x = (tid >= o) ? sc[tid - o] : 0;
            __syncthreads();
            sc[tid] += x;
            __syncthreads();
        }
        const int ex = tid ? sc[tid - 1] : 0;
        if (k0     < NKEY) off[k0]     = ex;
        if (k0 + 1 < NKEY) off[k0 + 1] = ex + c0;
        if (tid == BLOCK - 1) bsum[b] = sc[BLOCK - 1];
    }
    grid.sync();

    // ---------------- P2b: block 0 scans the 391 chunk sums ---------------
    if (blockIdx.x == 0) {
        const int i0 = 2 * tid;
        int a0 = (i0     < SCAN_BLOCKS) ? bsum[i0]     : 0;
        int a1 = (i0 + 1 < SCAN_BLOCKS) ? bsum[i0 + 1] : 0;
        sc[tid] = a0 + a1;
        __syncthreads();
        for (int o = 1; o < BLOCK; o <<= 1) {
            const int x = (tid >= o) ? sc[tid - o] : 0;
            __syncthreads();
            sc[tid] += x;
            __syncthreads();
        }
        const int ex = tid ? sc[tid - 1] : 0;
        bpre[i0]     = ex;
        bpre[i0 + 1] = ex + a0;
        if (tid == BLOCK - 1) off[NKEY] = sc[BLOCK - 1];   // grand total
    }
    grid.sync();

    // ---------------- P2c: add back chunk prefixes; init cursor -----------
    for (int key = g; key < NKEY; key += NTHREADS) {
        const int v = off[key] + bpre[key >> 9];
        off[key]    = v;
        cursor[key] = v;
    }
    grid.sync();

    // ---------------- P3: scatter entries grouped by key -------------------
    for (int e = g; e < N_EDGES; e += NTHREADS) {
        const int s = esrc[e];
        const int d = edst[e];
        float yx, yy, yz;
        edge_geom(pos, s, d, yx, yy, yz);
        #pragma unroll
        for (int k = 0; k < KPTS; ++k) {
            const float dx = yx - kp[k * 3 + 0];
            const float dy = yy - kp[k * 3 + 1];
            const float dz = yz - kp[k * 3 + 2];
            const float dist = sqrtf(dx * dx + dy * dy + dz * dz);
            const float m = 1.0f - dist * (1.0f / KP_EXTENT);
            if (m > 0.0f) {
                const int idx = atomicAdd(&cursor[(k & 3) * N_NODES + d], 1);
                if (idx < ECAP) {
                    const unsigned x = (unsigned)s | ((unsigned)(k >> 2) << 16)
                                     | ((unsigned)(d & 31) << 18);
                    entries[idx] = make_uint2(x, __float_as_uint(m));
                }
            }
        }
    }
    grid.sync();

    // ---------------- P4: gather + matmul + store --------------------------
    const int lane = tid & 63;
    const int wv   = tid >> 6;          // = k residue class

    // wave-resident W columns: k = wv + 4*kq, kq = 0..3  (128 VGPRs)
    float w0[IN_DIM], w1[IN_DIM], w2[IN_DIM], w3[IN_DIM];
    #pragma unroll
    for (int i = 0; i < IN_DIM; ++i) {
        w0[i] = W[(wv + 0)  * (IN_DIM * OUT_DIM) + i * OUT_DIM + lane];
        w1[i] = W[(wv + 4)  * (IN_DIM * OUT_DIM) + i * OUT_DIM + lane];
        w2[i] = W[(wv + 8)  * (IN_DIM * OUT_DIM) + i * OUT_DIM + lane];
        w3[i] = (wv + 12 < KPTS)
              ? W[(wv + 12) * (IN_DIM * OUT_DIM) + i * OUT_DIM + lane] : 0.0f;
    }

    for (int batch = blockIdx.x; batch < NBATCH; batch += GRID) {
        const int d0 = batch * 32;
        const int nd = min(32, N_NODES - d0);

        for (int i = tid; i < 4 * 32 * OUT_DIM; i += BLOCK) sacc[i] = 0.0f;
        __syncthreads();

        int start = off[wv * N_NODES + d0];
        int end   = off[wv * N_NODES + min(d0 + 32, N_NODES)];
        start = min(start, ECAP);
        end   = min(end, ECAP);

        int p = start;
        while (p < end) {
            const int nproc = min(64, end - p);
            uint2 ent = make_uint2(0u, 0u);
            if (p + lane < end) ent = entries[p + lane];   // coalesced bulk load

            #pragma unroll 2
            for (int j = 0; j < nproc; ++j) {
                const int ex = __builtin_amdgcn_readfirstlane(__shfl((int)ent.x, j));
                const float m = __uint_as_float(
                    __builtin_amdgcn_readfirstlane(__shfl((int)ent.y, j)));
                const int s  = ex & 0xFFFF;
                const int kq = (ex >> 16) & 3;
                const int dl = (ex >> 18) & 31;
                const float* __restrict__ f = feat + (s << 5);  // uniform -> s_load

                float c = 0.0f;
                if (kq == 0) {
                    #pragma unroll
                    for (int i = 0; i < IN_DIM; ++i) c = fmaf(f[i], w0[i], c);
                } else if (kq == 1) {
                    #pragma unroll
                    for (int i = 0; i < IN_DIM; ++i) c = fmaf(f[i], w1[i], c);
                } else if (kq == 2) {
                    #pragma unroll
                    for (int i = 0; i < IN_DIM; ++i) c = fmaf(f[i], w2[i], c);
                } else {
                    #pragma unroll
                    for (int i = 0; i < IN_DIM; ++i) c = fmaf(f[i], w3[i], c);
                }
                const int ai = (wv * 32 + dl) * OUT_DIM + lane;
                sacc[ai] += m * c;      // wave-private quarter, same-lane RMW
            }
            p += nproc;
        }
        __syncthreads();

        const int lim = nd * OUT_DIM;
        for (int i = tid; i < lim; i += BLOCK) {
            const int dl = i >> 6;
            const int o  = i & 63;
            const float v = sacc[(0 * 32 + dl) * OUT_DIM + o]
                          + sacc[(1 * 32 + dl) * OUT_DIM + o]
                          + sacc[(2 * 32 + dl) * OUT_DIM + o]
                          + sacc[(3 * 32 + dl) * OUT_DIM + o];
            out[(size_t)(d0 + dl) * OUT_DIM + o] = v;
        }
        __syncthreads();
    }
}

// ---------------------------------------------------------------------------
extern "C" void kernel_launch(void* const* d_in, const int* in_sizes, int n_in,
                              void* d_out, int out_size, void* d_ws, size_t ws_size,
                              hipStream_t stream)
{
    const float* pos  = (const float*)d_in[0];
    const float* feat = (const float*)d_in[1];
    const float* kp   = (const float*)d_in[2];
    const float* W    = (const float*)d_in[3];
    const int* esrc   = (const int*)d_in[4];
    const int* edst   = (const int*)d_in[5];
    float* out        = (float*)d_out;

    int*   cnt     = (int*)((char*)d_ws + CNT_OFF);
    int*   off     = (int*)((char*)d_ws + OFF_OFF);
    int*   cursor  = (int*)((char*)d_ws + CUR_OFF);
    int*   bsum    = (int*)((char*)d_ws + BSUM_OFF);
    int*   bpre    = (int*)((char*)d_ws + BPRE_OFF);
    uint2* entries = (uint2*)((char*)d_ws + ENT_OFF);

    hipMemsetAsync(cnt, 0, NKEY * sizeof(int), stream);

    void* args[] = { (void*)&pos, (void*)&feat, (void*)&kp, (void*)&W,
                     (void*)&esrc, (void*)&edst, (void*)&cnt, (void*)&off,
                     (void*)&cursor, (void*)&bsum, (void*)&bpre,
                     (void*)&entries, (void*)&out };
    hipLaunchCooperativeKernel((void*)kpconv_fused, dim3(GRID), dim3(BLOCK),
                               args, 0, stream);
}

// Round 6
// 188.600 us; speedup vs baseline: 2.5329x; 2.5329x over previous
//
#include <hip/hip_runtime.h>

#define N_NODES 50000
#define N_EDGES 800000
#define KPTS 15
#define IN_DIM 32
#define OUT_DIM 64
#define KP_EXTENT 0.6f
#define EXT2 (KP_EXTENT * KP_EXTENT)

#define DBLK 32                                   // dst nodes per bucket
#define NBKT ((N_NODES + DBLK - 1) / DBLK)        // 1563 buckets
#define NRES 4                                    // k-residue classes (k & 3)
#define CAP 256                                   // entries per (bucket,res); mean ~31

// ws layout: cnt int[NBKT*NRES] @ 0 ; entries uint2[NBKT*NRES*CAP] @ ENT_OFF
#define CNT_BYTES (NBKT * NRES * 4)               // 25008
#define ENT_OFF 32768                             // 8B-aligned, past counters

// ---------------------------------------------------------------------------
// K1: per-edge geometry -> bucket-scatter of active (edge,k) pairs.
// entry.x = src | (dst&31)<<16 | (k>>2)<<21 ; entry.y = bitcast(m)
// ---------------------------------------------------------------------------
__global__ __launch_bounds__(256) void scatter_pairs(
    const float* __restrict__ pos,
    const float* __restrict__ kp,
    const int*   __restrict__ esrc,
    const int*   __restrict__ edst,
    int*         __restrict__ cnt,
    uint2*       __restrict__ entries)
{
    const int e = blockIdx.x * 256 + threadIdx.x;   // 3125 blocks cover E exactly
    const int s = esrc[e];
    const int d = edst[e];

    const float yx = pos[s * 3 + 0] - pos[d * 3 + 0];
    const float yy = pos[s * 3 + 1] - pos[d * 3 + 1];
    const float yz = pos[s * 3 + 2] - pos[d * 3 + 2];

    const int bkt = d >> 5;
    const unsigned dl = (unsigned)(d & 31);
    const unsigned sl = (unsigned)s | (dl << 16);

    #pragma unroll
    for (int k = 0; k < KPTS; ++k) {
        const float dx = yx - kp[k * 3 + 0];
        const float dy = yy - kp[k * 3 + 1];
        const float dz = yz - kp[k * 3 + 2];
        const float d2 = dx * dx + dy * dy + dz * dz;
        if (d2 < EXT2) {                            // rare (~1.6%); sqrt only here
            const float m = 1.0f - sqrtf(d2) * (1.0f / KP_EXTENT);
            const int key = bkt * NRES + (k & 3);
            const int idx = atomicAdd(&cnt[key], 1);
            if (idx < CAP)
                entries[(size_t)key * CAP + idx] =
                    make_uint2(sl | ((unsigned)(k >> 2) << 21),
                               __float_as_uint(m));
        }
    }
}

// ---------------------------------------------------------------------------
// K2: one block per 32-dst bucket; wave r consumes residue-r entries with its
// 4 W-columns register-resident; wave-uniform entry/feat reads (scalar path);
// LDS wave-private accumulator; 4-way reduce + coalesced store. No atomics
// on the output path.
// ---------------------------------------------------------------------------
__global__ __launch_bounds__(256) void gather_mm(
    const float* __restrict__ feat,
    const float* __restrict__ W,        // [15][32][64]
    const int*   __restrict__ cnt,
    const uint2* __restrict__ entries,
    float*       __restrict__ out)
{
    __shared__ float sacc[NRES * DBLK * OUT_DIM];   // 32 KB

    const int tid  = threadIdx.x;
    const int lane = tid & 63;
    const int wv   = __builtin_amdgcn_readfirstlane(tid >> 6);  // force SGPR
    const int bkt  = blockIdx.x;

    // W columns for k = wv + 4*kq, kq=0..3 (k=15 slot zeroed; never selected)
    float w0[IN_DIM], w1[IN_DIM], w2[IN_DIM], w3[IN_DIM];
    #pragma unroll
    for (int i = 0; i < IN_DIM; ++i) {
        w0[i] = W[(wv + 0)  * (IN_DIM * OUT_DIM) + i * OUT_DIM + lane];
        w1[i] = W[(wv + 4)  * (IN_DIM * OUT_DIM) + i * OUT_DIM + lane];
        w2[i] = W[(wv + 8)  * (IN_DIM * OUT_DIM) + i * OUT_DIM + lane];
        w3[i] = (wv + 12 < KPTS)
              ? W[(wv + 12) * (IN_DIM * OUT_DIM) + i * OUT_DIM + lane] : 0.0f;
    }

    for (int i = tid; i < NRES * DBLK * OUT_DIM; i += 256) sacc[i] = 0.0f;
    __syncthreads();

    const int key = bkt * NRES + wv;
    const int n   = min(cnt[key], CAP);             // uniform scalar load
    const uint2* __restrict__ ebase = entries + (size_t)key * CAP;
    float* __restrict__ sq = sacc + wv * (DBLK * OUT_DIM);

    #pragma unroll 2
    for (int p = 0; p < n; ++p) {
        const uint2 ent = ebase[p];                 // wave-uniform -> s_load
        const unsigned ex = ent.x;
        const float m  = __uint_as_float(ent.y);
        const int s    = (int)(ex & 0xFFFFu);
        const int dl   = (int)((ex >> 16) & 31u);
        const int kq   = (int)((ex >> 21) & 3u);
        const float* __restrict__ f = feat + (s << 5);   // uniform row

        float c = 0.0f;
        if (kq == 0) {
            #pragma unroll
            for (int i = 0; i < IN_DIM; ++i) c = fmaf(f[i], w0[i], c);
        } else if (kq == 1) {
            #pragma unroll
            for (int i = 0; i < IN_DIM; ++i) c = fmaf(f[i], w1[i], c);
        } else if (kq == 2) {
            #pragma unroll
            for (int i = 0; i < IN_DIM; ++i) c = fmaf(f[i], w2[i], c);
        } else {
            #pragma unroll
            for (int i = 0; i < IN_DIM; ++i) c = fmaf(f[i], w3[i], c);
        }
        atomicAdd(&sq[dl * OUT_DIM + lane], m * c);  // ds_add, 2-way bank = free
    }
    __syncthreads();

    const int d0 = bkt * DBLK;
    const int nd = min(DBLK, N_NODES - d0);
    const int lim = nd * OUT_DIM;
    for (int i = tid; i < lim; i += 256) {
        const float v = sacc[0 * (DBLK * OUT_DIM) + i]
                      + sacc[1 * (DBLK * OUT_DIM) + i]
                      + sacc[2 * (DBLK * OUT_DIM) + i]
                      + sacc[3 * (DBLK * OUT_DIM) + i];
        out[(size_t)d0 * OUT_DIM + i] = v;
    }
}

// ---------------------------------------------------------------------------
extern "C" void kernel_launch(void* const* d_in, const int* in_sizes, int n_in,
                              void* d_out, int out_size, void* d_ws, size_t ws_size,
                              hipStream_t stream)
{
    const float* pos  = (const float*)d_in[0];   // [50000,3]
    const float* feat = (const float*)d_in[1];   // [50000,32]
    const float* kp   = (const float*)d_in[2];   // [15,3]
    const float* W    = (const float*)d_in[3];   // [15,32,64]
    const int* esrc   = (const int*)d_in[4];     // [800000]
    const int* edst   = (const int*)d_in[5];     // [800000]
    float* out        = (float*)d_out;           // [50000,64]

    int*   cnt     = (int*)d_ws;
    uint2* entries = (uint2*)((char*)d_ws + ENT_OFF);

    hipMemsetAsync(cnt, 0, CNT_BYTES, stream);

    scatter_pairs<<<N_EDGES / 256, 256, 0, stream>>>(pos, kp, esrc, edst,
                                                     cnt, entries);
    gather_mm<<<NBKT, 256, 0, stream>>>(feat, W, cnt, entries, out);
}

// Round 7
// 187.671 us; speedup vs baseline: 2.5455x; 1.0050x over previous
//
#include <hip/hip_runtime.h>

#define N_NODES 50000
#define N_EDGES 800000
#define KPTS 15
#define IN_DIM 32
#define OUT_DIM 64
#define KP_EXTENT 0.6f
#define EXT2 (KP_EXTENT * KP_EXTENT)

#define DBLK 32                                   // dst nodes per bucket
#define NBKT ((N_NODES + DBLK - 1) / DBLK)        // 1563 buckets
#define NKEY (NBKT * KPTS)                        // 23445 (bucket, k) keys
#define CAPK 64                                   // entries per key; mean ~8.3

// ws layout: cnt int[NKEY] @ 0 ; entries uint2[NKEY*CAPK] @ ENT_OFF (12 MB)
#define CNT_BYTES (NKEY * 4)                      // 93780
#define ENT_OFF 131072

// ---------------------------------------------------------------------------
// K1: per-edge geometry -> scatter active (edge,k) pairs into (bucket,k) bins.
// entry.x = src | (dst&31)<<16 ; entry.y = bitcast(m)
// ---------------------------------------------------------------------------
__global__ __launch_bounds__(256) void scatter_pairs(
    const float* __restrict__ pos,
    const float* __restrict__ kp,
    const int*   __restrict__ esrc,
    const int*   __restrict__ edst,
    int*         __restrict__ cnt,
    uint2*       __restrict__ entries)
{
    const int e = blockIdx.x * 256 + threadIdx.x;   // 3125 blocks cover E exactly
    const int s = esrc[e];
    const int d = edst[e];

    const float yx = pos[s * 3 + 0] - pos[d * 3 + 0];
    const float yy = pos[s * 3 + 1] - pos[d * 3 + 1];
    const float yz = pos[s * 3 + 2] - pos[d * 3 + 2];

    const int keybase = (d >> 5) * KPTS;
    const unsigned sl = (unsigned)s | ((unsigned)(d & 31) << 16);

    #pragma unroll
    for (int k = 0; k < KPTS; ++k) {
        const float dx = yx - kp[k * 3 + 0];
        const float dy = yy - kp[k * 3 + 1];
        const float dz = yz - kp[k * 3 + 2];
        const float d2 = dx * dx + dy * dy + dz * dz;
        if (d2 < EXT2) {                            // rare (~1.6%)
            const float m = 1.0f - sqrtf(d2) * (1.0f / KP_EXTENT);
            const int key = keybase + k;
            const int idx = atomicAdd(&cnt[key], 1);
            if (idx < CAPK)
                entries[(size_t)key * CAPK + idx] =
                    make_uint2(sl, __float_as_uint(m));
        }
    }
}

// ---------------------------------------------------------------------------
// K2: one block per 32-dst bucket. Wave wv walks k = wv, wv+4, ... ; per
// k-segment a single 32-float W column is live (no spill pressure, no
// branches). 2-entry ILP so the scalar feat-row load chains overlap.
// Shared 8 KB accumulator with LDS atomics; coalesced final store.
// ---------------------------------------------------------------------------
__global__ __launch_bounds__(256) void gather_mm(
    const float* __restrict__ feat,
    const float* __restrict__ W,        // [15][32][64]
    const int*   __restrict__ cnt,
    const uint2* __restrict__ entries,
    float*       __restrict__ out)
{
    __shared__ float sacc[DBLK * OUT_DIM];          // 8 KB

    const int tid  = threadIdx.x;
    const int lane = tid & 63;
    const int wv   = __builtin_amdgcn_readfirstlane(tid >> 6);
    const int bkt  = blockIdx.x;

    for (int i = tid; i < DBLK * OUT_DIM; i += 256) sacc[i] = 0.0f;
    __syncthreads();

    for (int k = wv; k < KPTS; k += 4) {
        const int key = bkt * KPTS + k;
        const int n   = min(cnt[key], CAPK);        // uniform scalar load
        if (n == 0) continue;
        const uint2* __restrict__ eb = entries + (size_t)key * CAPK;

        float w[IN_DIM];                            // 32 VGPRs, single live set
        #pragma unroll
        for (int i = 0; i < IN_DIM; ++i)
            w[i] = W[k * (IN_DIM * OUT_DIM) + i * OUT_DIM + lane];

        int p = 0;
        for (; p + 2 <= n; p += 2) {
            const uint2 ea = eb[p];                 // wave-uniform -> s_load
            const uint2 ec = eb[p + 1];
            const int sa = __builtin_amdgcn_readfirstlane((int)(ea.x & 0xFFFFu));
            const int sc = __builtin_amdgcn_readfirstlane((int)(ec.x & 0xFFFFu));
            const float* __restrict__ fa = feat + (sa << 5);
            const float* __restrict__ fc = feat + (sc << 5);

            float ca = 0.0f, cc = 0.0f;
            #pragma unroll
            for (int i = 0; i < IN_DIM; ++i) {      // two independent chains
                ca = fmaf(fa[i], w[i], ca);
                cc = fmaf(fc[i], w[i], cc);
            }
            const float ma = __uint_as_float(ea.y);
            const float mc = __uint_as_float(ec.y);
            const int dla = (int)((ea.x >> 16) & 31u);
            const int dlc = (int)((ec.x >> 16) & 31u);
            atomicAdd(&sacc[dla * OUT_DIM + lane], ma * ca);   // ds_add, free 2-way
            atomicAdd(&sacc[dlc * OUT_DIM + lane], mc * cc);
        }
        if (p < n) {
            const uint2 ea = eb[p];
            const int sa = __builtin_amdgcn_readfirstlane((int)(ea.x & 0xFFFFu));
            const float* __restrict__ fa = feat + (sa << 5);
            float ca = 0.0f;
            #pragma unroll
            for (int i = 0; i < IN_DIM; ++i) ca = fmaf(fa[i], w[i], ca);
            const float ma = __uint_as_float(ea.y);
            const int dla = (int)((ea.x >> 16) & 31u);
            atomicAdd(&sacc[dla * OUT_DIM + lane], ma * ca);
        }
    }
    __syncthreads();

    const int d0  = bkt * DBLK;
    const int nd  = min(DBLK, N_NODES - d0);
    const int lim = nd * OUT_DIM;
    for (int i = tid; i < lim; i += 256)
        out[(size_t)d0 * OUT_DIM + i] = sacc[i];
}

// ---------------------------------------------------------------------------
extern "C" void kernel_launch(void* const* d_in, const int* in_sizes, int n_in,
                              void* d_out, int out_size, void* d_ws, size_t ws_size,
                              hipStream_t stream)
{
    const float* pos  = (const float*)d_in[0];   // [50000,3]
    const float* feat = (const float*)d_in[1];   // [50000,32]
    const float* kp   = (const float*)d_in[2];   // [15,3]
    const float* W    = (const float*)d_in[3];   // [15,32,64]
    const int* esrc   = (const int*)d_in[4];     // [800000]
    const int* edst   = (const int*)d_in[5];     // [800000]
    float* out        = (float*)d_out;           // [50000,64]

    int*   cnt     = (int*)d_ws;
    uint2* entries = (uint2*)((char*)d_ws + ENT_OFF);

    hipMemsetAsync(cnt, 0, CNT_BYTES, stream);

    scatter_pairs<<<N_EDGES / 256, 256, 0, stream>>>(pos, kp, esrc, edst,
                                                     cnt, entries);
    gather_mm<<<NBKT, 256, 0, stream>>>(feat, W, cnt, entries, out);
}